// Round 7
// baseline (246.035 us; speedup 1.0000x reference)
//
#include <hip/hip_runtime.h>

// LocallyConnected2d: out[i,j] = sum_{kh,kw} x[i+kh, j+kw] * W[i,j,kh,kw]
// x: (450,450) f32 (810 KB), W: (436,436,15,15) f32 (171 MB, streamed once).
// HBM-bound: floor ~= 171 MB / 6.9 TB/s ~= 25-27 us. R4/R5/R6 plateau at
// kernel ~34 us with per-quad structures.
//
// R7: one wave per RUN of 16 quads (64 consecutive outputs in ONE output
// row; 109 quads/row = 6x16 + 1x13 -> 7 runs/row, 3052 runs total).
//  - x patch 15x78 staged ONCE per run (19 VMEM), amortized over 16 quads
//    (1.2 VMEM/quad vs 5 in R4/R6 -> kills the 5x-redundant x staging).
//  - W: 4 global_load_dwordx4 per quad, prefetched one quad ahead so the
//    HBM stream stays in flight across each quad's compute+reduction.
//  - LDS row stride 81 (odd phase per kh row) scatters the stride-4 read
//    pattern across banks.
//  - Compute core + 14-shuffle packed reduction verified in R3/R4/R6.
//    LDS addr = kh*81 + kw + 4j + s = k + 66*kh + 4j + s.

constexpr int IN_W = 450;
constexpr int OW = 436;
constexpr int SLDS = 81;                 // padded LDS row stride
constexpr int PATCH = 15 * SLDS;         // 1215 floats/wave
constexpr int NRUN = 436 * 7;            // 3052 runs; grid exact

__global__ __launch_bounds__(256)
void lc2d_run16(const float* __restrict__ x,
                const float* __restrict__ W,
                float* __restrict__ out) {
    __shared__ float patch[4][PATCH];    // 19.44 KB/block

    const int lane = threadIdx.x & 63;
    const int wid = threadIdx.x >> 6;
    const int r = blockIdx.x * 4 + wid;  // 0..3051

    const int i = (int)((unsigned)r / 7u);   // output row
    const int u = r - i * 7;                 // run within row
    const int jq0 = u * 16;                  // first quad in row: 0,16,..,96
    const int len = (u == 6) ? 13 : 16;
    const int q0 = i * 109 + jq0;            // global quad index
    const int o0 = i * OW + 4 * jq0;         // first output index
    const int xcol0 = 4 * jq0;

    // ---- stage x patch: rows i..i+14, cols xcol0..xcol0+77 (stride 81) ----
    float* lp = patch[wid];
#pragma unroll
    for (int p = 0; p < 19; ++p) {
        const int i2 = lane + 64 * p;        // 0..1169
        if (p < 18 || i2 < 1170) {
            const unsigned r2 = (unsigned)i2 / 78u;   // magic-mul
            const int c2 = i2 - (int)r2 * 78;
            int xc = xcol0 + c2;
            xc = xc > 449 ? 449 : xc;        // clamp (clamped cols never read)
            lp[(int)r2 * SLDS + c2] = x[(i + (int)r2) * IN_W + xc];
        }
    }

    // ---- W prefetch for quad 0 ----
    const float4* __restrict__ W4 = (const float4*)W;
    size_t wb = (size_t)q0 * 225;
    float4 cw0 = W4[wb + lane];
    float4 cw1 = W4[wb + 64 + lane];
    float4 cw2 = W4[wb + 128 + lane];
    float4 cw3 = make_float4(0.f, 0.f, 0.f, 0.f);
    if (lane < 33) cw3 = W4[wb + 192 + lane];

    __builtin_amdgcn_wave_barrier();     // slab wave-private; DS ops in-order

    const int el4 = lane * 4;
    for (int j = 0; j < len; ++j) {
        // ---- prefetch next quad's W (keeps HBM stream in flight) ----
        const int jn = (j + 1 < len) ? j + 1 : j;   // last iter: L1-hot reload
        const size_t nwb = (size_t)(q0 + jn) * 225;
        float4 nw0 = W4[nwb + lane];
        float4 nw1 = W4[nwb + 64 + lane];
        float4 nw2 = W4[nwb + 128 + lane];
        float4 nw3 = make_float4(0.f, 0.f, 0.f, 0.f);
        if (lane < 33) nw3 = W4[nwb + 192 + lane];

        // ---- compute quad j ----
        float acc[4] = {0.f, 0.f, 0.f, 0.f};
        {
            const float4 wqs[3] = {cw0, cw1, cw2};
#pragma unroll
            for (int t = 0; t < 3; ++t) {
                const float wv4[4] = {wqs[t].x, wqs[t].y, wqs[t].z, wqs[t].w};
#pragma unroll
                for (int c = 0; c < 4; ++c) {
                    const bool b = (el4 + c) >= (225 - 31 * t);
                    const unsigned k = (unsigned)(el4 + c + 31 * t - (b ? 225 : 0));
                    const unsigned kh = k / 15u;          // magic-mul
                    const int addr = (int)(k + 66u * kh) + 4 * j + t + (b ? 1 : 0);
                    const float pr = wv4[c] * lp[addr];
                    if (b) acc[t + 1] += pr; else acc[t] += pr;
                }
            }
        }
        if (lane < 33) {                     // elements 768..899, segment 3
            const float wv4[4] = {cw3.x, cw3.y, cw3.z, cw3.w};
#pragma unroll
            for (int c = 0; c < 4; ++c) {
                const unsigned k = (unsigned)(el4 + c + 93);   // 93..224
                const unsigned kh = k / 15u;
                const int addr = (int)(k + 66u * kh) + 4 * j + 3;
                acc[3] = fmaf(wv4[c], lp[addr], acc[3]);
            }
        }

        // ---- 14-shuffle packed reduction ----
#pragma unroll
        for (int a = 0; a < 4; ++a) acc[a] += __shfl_xor(acc[a], 32, 64);
        float zA = (lane < 32) ? acc[0] : acc[1];
        float zB = (lane < 32) ? acc[2] : acc[3];
#pragma unroll
        for (int off = 16; off > 0; off >>= 1) {
            zA += __shfl_xor(zA, off, 64);
            zB += __shfl_xor(zB, off, 64);
        }
        const int ob = o0 + 4 * j;
        if (lane == 0)  { out[ob]     = zA; out[ob + 2] = zB; }
        if (lane == 32) { out[ob + 1] = zA; out[ob + 3] = zB; }

        cw0 = nw0; cw1 = nw1; cw2 = nw2; cw3 = nw3;
    }
}

extern "C" void kernel_launch(void* const* d_in, const int* in_sizes, int n_in,
                              void* d_out, int out_size, void* d_ws, size_t ws_size,
                              hipStream_t stream) {
    const float* x = (const float*)d_in[0];  // (450,450)
    const float* W = (const float*)d_in[1];  // (436,436,15,15)
    float* out = (float*)d_out;              // (436,436)

    const int nblocks = NRUN / 4;            // 763, exact (3052 waves)
    lc2d_run16<<<nblocks, 256, 0, stream>>>(x, W, out);
}

// Round 8
// 228.150 us; speedup vs baseline: 1.0784x; 1.0784x over previous
//
#include <hip/hip_runtime.h>

// LocallyConnected2d: out[i,j] = sum_{kh,kw} x[i+kh, j+kw] * W[i,j,kh,kw]
// x: (450,450) f32 (810 KB, cache-resident), W: (436,436,15,15) f32 (171 MB,
// streamed exactly once) -> HBM-bound, floor ~= 171 MB / 6.9 TB/s ~= 25-27 us.
//
// R8 = R4 (best measured: 234.4 us total) + nontemporal hints on the W
// stream and output stores. R5 (2-quad pipeline), R6 (dwordx4 W), R7
// (run-of-16 amortization) were all neutral-to-worse: the structure is at
// its plateau; the only untried lever is the cache-allocation policy of the
// single-pass 171 MB W read (nt bypasses L1/L2 allocation, keeps x hot).
//
// Structure (verified R4): wave-per-quad, stride-1 scalar W loads
// (lane + 64t, t=0..13 + 4-lane tail), x via per-wave 15x18 LDS patch,
// compile-time segment boundaries (t=3 lane33, t=7 lane2, t=10 lane35),
// 14-shuffle packed reduction.

constexpr int IN_W = 450;
constexpr int OW = 436;
constexpr int NQUAD = (436 * 436) / 4;   // 47524 = 11881 blocks * 4 waves, exact

__global__ __launch_bounds__(256, 6)
void lc2d_quad_lds_nt(const float* __restrict__ x,
                      const float* __restrict__ W,
                      float* __restrict__ out) {
    __shared__ float patch[4][270];      // 15 rows x 18 cols per wave, 4.3 KB

    const int lane = threadIdx.x & 63;
    const int wv = threadIdx.x >> 6;
    const int q = blockIdx.x * 4 + wv;   // grid is exact: no bounds check

    const int o0 = q * 4;
    const int oi = o0 / OW;              // magic-mul
    const int oj = o0 - oi * OW;         // multiple of 4 -> quad never wraps row
    const int xb0 = oi * IN_W + oj;

    const float* __restrict__ Wq = W + (size_t)o0 * 225;   // q*900 floats

    // ---- W loads: single-use stream -> nontemporal (no L1/L2 allocate) ----
    float wreg[14];
#pragma unroll
    for (int t = 0; t < 14; ++t)
        wreg[t] = __builtin_nontemporal_load(&Wq[lane + 64 * t]);
    float wtail = (lane < 4) ? __builtin_nontemporal_load(&Wq[896 + lane]) : 0.0f;

    // ---- stage x patch 15x18 into this wave's LDS slab ----
    float* lp = patch[wv];
#pragma unroll
    for (int p = 0; p < 5; ++p) {
        const int i = lane + 64 * p;     // 0..269 (p=4: lanes 0..13)
        if (p < 4 || i < 270) {
            const unsigned r = (unsigned)i / 18u;   // magic-mul
            const int c = i - (int)r * 18;
            lp[i] = x[xb0 + (int)r * IN_W + c];
        }
    }
    __syncthreads();   // R4-exact (block barrier; proven config)

    // ---- compute: element e = lane + 64t, segment s = e/225 ----
    constexpr int S0[14] = {0,0,0,0, 1,1,1,1, 2,2,2, 3,3,3};
    constexpr int BL[14] = {64,64,64,33, 64,64,64,2, 64,64,35, 64,64,64};
    constexpr int K0[14] = {0,64,128,192, 31,95,159,223, 62,126,190, 29,93,157};

    float acc[4] = {0.f, 0.f, 0.f, 0.f};
#pragma unroll
    for (int t = 0; t < 14; ++t) {
        const bool b = (BL[t] != 64) && (lane >= BL[t]);
        const unsigned k = (unsigned)(lane + K0[t] - (b ? 225 : 0)); // in [0,225)
        const unsigned kh = k / 15u;                                  // magic-mul
        const int addr = (int)(k + 3u * kh) + S0[t] + (b ? 1 : 0);    // kh*18+kw+s
        const float pr = wreg[t] * lp[addr];
        if (BL[t] == 64) {
            acc[S0[t]] += pr;                  // compile-time index
        } else {
            if (b) acc[S0[t] + 1] += pr; else acc[S0[t]] += pr;
        }
    }
    // tail: e = 896..899 on lanes 0..3 -> s=3, k=221..224, kh=14, kw=11..14
    if (lane < 4) {
        acc[3] = fmaf(wtail, lp[266 + lane], acc[3]);  // 14*18 + (kw+3)
    }

    // ---- reduction: 14 shuffles total ----
#pragma unroll
    for (int a = 0; a < 4; ++a) acc[a] += __shfl_xor(acc[a], 32, 64);
    float zA = (lane < 32) ? acc[0] : acc[1];
    float zB = (lane < 32) ? acc[2] : acc[3];
#pragma unroll
    for (int off = 16; off > 0; off >>= 1) {
        zA += __shfl_xor(zA, off, 64);   // stays within each 32-lane half
        zB += __shfl_xor(zB, off, 64);
    }
    if (lane == 0) {
        __builtin_nontemporal_store(zA, &out[o0]);
        __builtin_nontemporal_store(zB, &out[o0 + 2]);
    }
    if (lane == 32) {
        __builtin_nontemporal_store(zA, &out[o0 + 1]);
        __builtin_nontemporal_store(zB, &out[o0 + 3]);
    }
}

extern "C" void kernel_launch(void* const* d_in, const int* in_sizes, int n_in,
                              void* d_out, int out_size, void* d_ws, size_t ws_size,
                              hipStream_t stream) {
    const float* x = (const float*)d_in[0];  // (450,450)
    const float* W = (const float*)d_in[1];  // (436,436,15,15)
    float* out = (float*)d_out;              // (436,436)

    const int nblocks = NQUAD / 4;           // 11881, exact
    lc2d_quad_lds_nt<<<nblocks, 256, 0, stream>>>(x, W, out);
}